// Round 1
// baseline (1095.816 us; speedup 1.0000x reference)
//
#include <hip/hip_runtime.h>

// 2-layer GCN: h1 = relu(Anorm @ (x@w1) + b1); out = Anorm @ (h1@w2) + b2
// Anorm includes self-loops + symmetric deg^-1/2 normalization.
// Strategy: device-built CSR (by dst) once per call; dinv folded into GEMM
// epilogue so aggregation is a pure gather-sum; one wave per node.

// ---------------- edge dtype detect (int32 vs int64) ----------------
__global__ void detect_i64(const int* __restrict__ idx32, int* __restrict__ flag) {
    // If edge_index is int64 (values < 2^31), every odd int32 word is 0.
    int v = idx32[2 * threadIdx.x + 1];
    unsigned long long b = __ballot(v != 0);
    if (threadIdx.x == 0) flag[0] = (b == 0ULL) ? 1 : 0;
}

__device__ __forceinline__ int load_idx(const void* edges, size_t i, int is64) {
    return is64 ? (int)((const long long*)edges)[i] : ((const int*)edges)[i];
}

// ---------------- degree histogram ----------------
__global__ void hist_kernel(const void* __restrict__ edges, int E,
                            const int* __restrict__ flag, int* __restrict__ deg) {
    int i = blockIdx.x * blockDim.x + threadIdx.x;
    if (i >= E) return;
    int is64 = flag[0];
    int d = load_idx(edges, (size_t)E + i, is64);
    atomicAdd(&deg[d], 1);
}

__global__ void dinv_kernel(const int* __restrict__ deg, float* __restrict__ dinv, int N) {
    int i = blockIdx.x * blockDim.x + threadIdx.x;
    if (i < N) dinv[i] = rsqrtf((float)(deg[i] + 1));  // +1 for self-loop
}

// ---------------- 3-kernel exclusive scan over deg -> rowptr ----------------
__global__ void scan_partials(const int* __restrict__ deg, int* __restrict__ partials, int N) {
    __shared__ int sm[256];
    int t = threadIdx.x, i = blockIdx.x * 256 + t;
    sm[t] = (i < N) ? deg[i] : 0;
    __syncthreads();
    for (int off = 128; off > 0; off >>= 1) {
        if (t < off) sm[t] += sm[t + off];
        __syncthreads();
    }
    if (t == 0) partials[blockIdx.x] = sm[0];
}

__global__ void scan_scan(int* __restrict__ partials, int NB) {  // 1 block, 512 thr
    __shared__ int sm[512];
    int t = threadIdx.x;
    int v = (t < NB) ? partials[t] : 0;
    sm[t] = v; __syncthreads();
    for (int off = 1; off < 512; off <<= 1) {
        int x = sm[t];
        int y = (t >= off) ? sm[t - off] : 0;
        __syncthreads();
        sm[t] = x + y;
        __syncthreads();
    }
    if (t < NB) partials[t] = (t == 0) ? 0 : sm[t - 1];  // exclusive
}

__global__ void scan_write(const int* __restrict__ deg, const int* __restrict__ partials,
                           int* __restrict__ rowptr, int* __restrict__ cursor, int N, int E) {
    __shared__ int sm[256];
    int t = threadIdx.x, b = blockIdx.x, i = b * 256 + t;
    int v = (i < N) ? deg[i] : 0;
    sm[t] = v; __syncthreads();
    for (int off = 1; off < 256; off <<= 1) {
        int x = sm[t];
        int y = (t >= off) ? sm[t - off] : 0;
        __syncthreads();
        sm[t] = x + y;
        __syncthreads();
    }
    int ex = partials[b] + sm[t] - v;  // exclusive
    if (i < N) { rowptr[i] = ex; cursor[i] = ex; }
    if (i == 0 && b == 0) rowptr[N] = E;
}

// ---------------- counting-sort fill: col[] grouped by dst ----------------
__global__ void fill_kernel(const void* __restrict__ edges, int E,
                            const int* __restrict__ flag, int* __restrict__ cursor,
                            int* __restrict__ colx) {
    int i = blockIdx.x * blockDim.x + threadIdx.x;
    if (i >= E) return;
    int is64 = flag[0];
    int s = load_idx(edges, (size_t)i, is64);
    int d = load_idx(edges, (size_t)E + i, is64);
    int pos = atomicAdd(&cursor[d], 1);
    colx[pos] = s;
}

// ---------------- GEMM: G = dinv .* (X @ W), K=128 fixed ----------------
// BM=64, BN=64, 256 threads, thread tile 4x4. X staged transposed in LDS.
__global__ __launch_bounds__(256) void gemm_scale(
    const float* __restrict__ X, const float* __restrict__ W,
    const float* __restrict__ dinv, float* __restrict__ G, int M, int Ncols) {
    constexpr int K = 128;
    __shared__ float xT[K][64];   // [k][row]
    __shared__ float ws[K][64];   // [k][col]
    const int t = threadIdx.x;
    const int m0 = blockIdx.x * 64;
    const int c0 = blockIdx.y * 64;

    // stage W tile (128 x 64)
    {
        int cl = (t & 15) * 4;
        int k0 = t >> 4;  // 0..15
        for (int kk = 0; kk < K; kk += 16) {
            int k = k0 + kk;
            float4 wv = *(const float4*)&W[(size_t)k * Ncols + c0 + cl];
            *(float4*)&ws[k][cl] = wv;
        }
    }
    // stage X tile transposed (64 rows x 128 k) -> xT[k][r]
    {
        int r = t & 63, cg = t >> 6;  // cg 0..3
        int row = m0 + r;
        bool valid = row < M;
        const float* xrow = &X[(size_t)(valid ? row : (M - 1)) * K];
        for (int cc = 0; cc < 8; ++cc) {
            int c = cg * 4 + cc * 16;
            float4 v;
            if (valid) v = *(const float4*)&xrow[c];
            else { v.x = v.y = v.z = v.w = 0.f; }
            xT[c + 0][r] = v.x; xT[c + 1][r] = v.y;
            xT[c + 2][r] = v.z; xT[c + 3][r] = v.w;
        }
    }
    __syncthreads();

    const int tc = (t & 15) * 4;
    const int tr = (t >> 4) * 4;
    float acc[4][4] = {};
#pragma unroll 8
    for (int k = 0; k < K; ++k) {
        float4 av = *(const float4*)&xT[k][tr];
        float4 bv = *(const float4*)&ws[k][tc];
        float a[4] = {av.x, av.y, av.z, av.w};
        float b[4] = {bv.x, bv.y, bv.z, bv.w};
#pragma unroll
        for (int i = 0; i < 4; ++i)
#pragma unroll
            for (int j = 0; j < 4; ++j)
                acc[i][j] = fmaf(a[i], b[j], acc[i][j]);
    }

#pragma unroll
    for (int i = 0; i < 4; ++i) {
        int row = m0 + tr + i;
        if (row < M) {
            float d = dinv[row];
            float4 o;
            o.x = acc[i][0] * d; o.y = acc[i][1] * d;
            o.z = acc[i][2] * d; o.w = acc[i][3] * d;
            *(float4*)&G[(size_t)row * Ncols + c0 + tc] = o;
        }
    }
}

// ---------------- aggregation: out[i] = dinv[i]*(sum_nbr g[src] + g[i]) + b ----------------
template <int F, bool RELU>
__global__ __launch_bounds__(256) void agg_kernel(
    const float* __restrict__ G, const int* __restrict__ rowptr,
    const int* __restrict__ colx, const float* __restrict__ dinv,
    const float* __restrict__ bias, float* __restrict__ Out, int N) {
    int wid = (int)((blockIdx.x * 256 + threadIdx.x) >> 6);  // one wave per node
    int lane = threadIdx.x & 63;
    if (wid >= N) return;
    int s = rowptr[wid], e = rowptr[wid + 1];
    if constexpr (F == 128) {
        float2 acc = *(const float2*)&G[(size_t)wid * F + lane * 2];  // self-loop term
        for (int j = s; j < e; ++j) {
            int c = colx[j];
            float2 v = *(const float2*)&G[(size_t)c * F + lane * 2];
            acc.x += v.x; acc.y += v.y;
        }
        float d = dinv[wid];
        float2 bv = *(const float2*)&bias[lane * 2];
        float ox = fmaf(d, acc.x, bv.x);
        float oy = fmaf(d, acc.y, bv.y);
        if (RELU) { ox = fmaxf(ox, 0.f); oy = fmaxf(oy, 0.f); }
        float2 o; o.x = ox; o.y = oy;
        *(float2*)&Out[(size_t)wid * F + lane * 2] = o;
    } else {  // F == 64
        float acc = G[(size_t)wid * F + lane];  // self
        for (int j = s; j < e; ++j) {
            int c = colx[j];
            acc += G[(size_t)c * F + lane];
        }
        float o = fmaf(dinv[wid], acc, bias[lane]);
        if (RELU) o = fmaxf(o, 0.f);
        Out[(size_t)wid * F + lane] = o;
    }
}

extern "C" void kernel_launch(void* const* d_in, const int* in_sizes, int n_in,
                              void* d_out, int out_size, void* d_ws, size_t ws_size,
                              hipStream_t stream) {
    const float* x  = (const float*)d_in[0];
    const void*  ei = d_in[1];
    const float* w1 = (const float*)d_in[2];
    const float* b1 = (const float*)d_in[3];
    const float* w2 = (const float*)d_in[4];
    const float* b2 = (const float*)d_in[5];
    float* out = (float*)d_out;

    const int N  = in_sizes[0] / 128;   // 100000
    const int E  = in_sizes[1] / 2;     // 3200000
    const int NB = (N + 255) / 256;     // scan blocks

    char* p = (char*)d_ws;
    auto carve = [&](size_t bytes) {
        void* r = (void*)p;
        p += (bytes + 255) & ~(size_t)255;
        return r;
    };
    int*   deg      = (int*)carve((size_t)N * 4);
    int*   rowptr   = (int*)carve((size_t)(N + 1) * 4);
    int*   cursor   = (int*)carve((size_t)N * 4);
    int*   partials = (int*)carve(512 * 4);
    int*   flag     = (int*)carve(256);
    float* dinv     = (float*)carve((size_t)N * 4);
    int*   colx     = (int*)carve((size_t)E * 4);
    float* g1       = (float*)carve((size_t)N * 128 * 4);
    float* a1       = (float*)carve((size_t)N * 128 * 4);
    float* g2       = g1;  // g1 dead after agg1; reuse for layer-2 GEMM output

    hipMemsetAsync(deg, 0, (size_t)N * 4, stream);
    detect_i64<<<1, 64, 0, stream>>>((const int*)ei, flag);
    hist_kernel<<<(E + 255) / 256, 256, 0, stream>>>(ei, E, flag, deg);
    dinv_kernel<<<(N + 255) / 256, 256, 0, stream>>>(deg, dinv, N);
    scan_partials<<<NB, 256, 0, stream>>>(deg, partials, N);
    scan_scan<<<1, 512, 0, stream>>>(partials, NB);
    scan_write<<<NB, 256, 0, stream>>>(deg, partials, rowptr, cursor, N, E);
    fill_kernel<<<(E + 255) / 256, 256, 0, stream>>>(ei, E, flag, cursor, colx);

    // layer 1: g1 = dinv .* (x @ w1); a1 = relu(dinv.*(gather-sum g1) + b1)
    dim3 grid1((N + 63) / 64, 2);
    gemm_scale<<<grid1, 256, 0, stream>>>(x, w1, dinv, g1, N, 128);
    agg_kernel<128, true><<<(N + 3) / 4, 256, 0, stream>>>(g1, rowptr, colx, dinv, b1, a1, N);

    // layer 2: g2 = dinv .* (a1 @ w2); out = dinv.*(gather-sum g2) + b2
    dim3 grid2((N + 63) / 64, 1);
    gemm_scale<<<grid2, 256, 0, stream>>>(a1, w2, dinv, g2, N, 64);
    agg_kernel<64, false><<<(N + 3) / 4, 256, 0, stream>>>(g2, rowptr, colx, dinv, b2, out, N);
}

// Round 2
// 851.137 us; speedup vs baseline: 1.2875x; 1.2875x over previous
//
#include <hip/hip_runtime.h>

// 2-layer GCN: h1 = relu(Anorm @ (x@w1) + b1); out = Anorm @ (h1@w2) + b2
// Anorm includes self-loops + symmetric deg^-1/2 normalization.
// Strategy: device-built CSR (by dst) per call; dinv folded into GEMM
// epilogue so aggregation is a pure gather-sum; one wave per node,
// edge loop batch-unrolled for memory-level parallelism (latency was the
// R1 bottleneck: 1 outstanding gather/wave -> 8.9 B/cy/CU).

// ---------------- edge dtype detect (int32 vs int64) ----------------
__global__ void detect_i64(const int* __restrict__ idx32, int* __restrict__ flag) {
    int v = idx32[2 * threadIdx.x + 1];
    unsigned long long b = __ballot(v != 0);
    if (threadIdx.x == 0) flag[0] = (b == 0ULL) ? 1 : 0;
}

__device__ __forceinline__ int load_idx(const void* edges, size_t i, int is64) {
    return is64 ? (int)((const long long*)edges)[i] : ((const int*)edges)[i];
}

// ---------------- degree histogram ----------------
__global__ void hist_kernel(const void* __restrict__ edges, int E,
                            const int* __restrict__ flag, int* __restrict__ deg) {
    int i = blockIdx.x * blockDim.x + threadIdx.x;
    if (i >= E) return;
    int is64 = flag[0];
    int d = load_idx(edges, (size_t)E + i, is64);
    atomicAdd(&deg[d], 1);
}

__global__ void dinv_kernel(const int* __restrict__ deg, float* __restrict__ dinv, int N) {
    int i = blockIdx.x * blockDim.x + threadIdx.x;
    if (i < N) dinv[i] = rsqrtf((float)(deg[i] + 1));  // +1 for self-loop
}

// ---------------- 3-kernel exclusive scan over deg -> rowptr ----------------
__global__ void scan_partials(const int* __restrict__ deg, int* __restrict__ partials, int N) {
    __shared__ int sm[256];
    int t = threadIdx.x, i = blockIdx.x * 256 + t;
    sm[t] = (i < N) ? deg[i] : 0;
    __syncthreads();
    for (int off = 128; off > 0; off >>= 1) {
        if (t < off) sm[t] += sm[t + off];
        __syncthreads();
    }
    if (t == 0) partials[blockIdx.x] = sm[0];
}

__global__ void scan_scan(int* __restrict__ partials, int NB) {  // 1 block, 512 thr
    __shared__ int sm[512];
    int t = threadIdx.x;
    int v = (t < NB) ? partials[t] : 0;
    sm[t] = v; __syncthreads();
    for (int off = 1; off < 512; off <<= 1) {
        int x = sm[t];
        int y = (t >= off) ? sm[t - off] : 0;
        __syncthreads();
        sm[t] = x + y;
        __syncthreads();
    }
    if (t < NB) partials[t] = (t == 0) ? 0 : sm[t - 1];  // exclusive
}

__global__ void scan_write(const int* __restrict__ deg, const int* __restrict__ partials,
                           int* __restrict__ rowptr, int* __restrict__ cursor, int N, int E) {
    __shared__ int sm[256];
    int t = threadIdx.x, b = blockIdx.x, i = b * 256 + t;
    int v = (i < N) ? deg[i] : 0;
    sm[t] = v; __syncthreads();
    for (int off = 1; off < 256; off <<= 1) {
        int x = sm[t];
        int y = (t >= off) ? sm[t - off] : 0;
        __syncthreads();
        sm[t] = x + y;
        __syncthreads();
    }
    int ex = partials[b] + sm[t] - v;  // exclusive
    if (i < N) { rowptr[i] = ex; cursor[i] = ex; }
    if (i == 0 && b == 0) rowptr[N] = E;
}

// ---------------- counting-sort fill: col[] grouped by dst ----------------
__global__ void fill_kernel(const void* __restrict__ edges, int E,
                            const int* __restrict__ flag, int* __restrict__ cursor,
                            int* __restrict__ colx) {
    int i = blockIdx.x * blockDim.x + threadIdx.x;
    if (i >= E) return;
    int is64 = flag[0];
    int s = load_idx(edges, (size_t)i, is64);
    int d = load_idx(edges, (size_t)E + i, is64);
    int pos = atomicAdd(&cursor[d], 1);
    colx[pos] = s;
}

// ---------------- GEMM: G = dinv .* (X @ W), K=128 fixed ----------------
__global__ __launch_bounds__(256) void gemm_scale(
    const float* __restrict__ X, const float* __restrict__ W,
    const float* __restrict__ dinv, float* __restrict__ G, int M, int Ncols) {
    constexpr int K = 128;
    __shared__ float xT[K][64];   // [k][row]
    __shared__ float ws[K][64];   // [k][col]
    const int t = threadIdx.x;
    const int m0 = blockIdx.x * 64;
    const int c0 = blockIdx.y * 64;

    {
        int cl = (t & 15) * 4;
        int k0 = t >> 4;
        for (int kk = 0; kk < K; kk += 16) {
            int k = k0 + kk;
            float4 wv = *(const float4*)&W[(size_t)k * Ncols + c0 + cl];
            *(float4*)&ws[k][cl] = wv;
        }
    }
    {
        int r = t & 63, cg = t >> 6;
        int row = m0 + r;
        bool valid = row < M;
        const float* xrow = &X[(size_t)(valid ? row : (M - 1)) * K];
        for (int cc = 0; cc < 8; ++cc) {
            int c = cg * 4 + cc * 16;
            float4 v;
            if (valid) v = *(const float4*)&xrow[c];
            else { v.x = v.y = v.z = v.w = 0.f; }
            xT[c + 0][r] = v.x; xT[c + 1][r] = v.y;
            xT[c + 2][r] = v.z; xT[c + 3][r] = v.w;
        }
    }
    __syncthreads();

    const int tc = (t & 15) * 4;
    const int tr = (t >> 4) * 4;
    float acc[4][4] = {};
#pragma unroll 8
    for (int k = 0; k < K; ++k) {
        float4 av = *(const float4*)&xT[k][tr];
        float4 bv = *(const float4*)&ws[k][tc];
        float a[4] = {av.x, av.y, av.z, av.w};
        float b[4] = {bv.x, bv.y, bv.z, bv.w};
#pragma unroll
        for (int i = 0; i < 4; ++i)
#pragma unroll
            for (int j = 0; j < 4; ++j)
                acc[i][j] = fmaf(a[i], b[j], acc[i][j]);
    }

#pragma unroll
    for (int i = 0; i < 4; ++i) {
        int row = m0 + tr + i;
        if (row < M) {
            float d = dinv[row];
            float4 o;
            o.x = acc[i][0] * d; o.y = acc[i][1] * d;
            o.z = acc[i][2] * d; o.w = acc[i][3] * d;
            *(float4*)&G[(size_t)row * Ncols + c0 + tc] = o;
        }
    }
}

// ------- aggregation: out[i] = dinv[i]*(sum_nbr g[src] + g[i]) + b -------
// One wave per node. Edge loop batch-unrolled: issue UNR independent row
// gathers before accumulating, to get UNR outstanding loads per wave.
template <int F, bool RELU, int UNR>
__global__ __launch_bounds__(256) void agg_kernel(
    const float* __restrict__ G, const int* __restrict__ rowptr,
    const int* __restrict__ colx, const float* __restrict__ dinv,
    const float* __restrict__ bias, float* __restrict__ Out, int N) {
    int wid = (int)((blockIdx.x * 256 + threadIdx.x) >> 6);
    int lane = threadIdx.x & 63;
    if (wid >= N) return;
    int s = rowptr[wid], e = rowptr[wid + 1];

    if constexpr (F == 128) {
        const float2* gl = (const float2*)G + lane;  // row stride 64 float2
        float2 acc = gl[wid << 6];                   // self-loop term
        float accx2 = 0.f, accy2 = 0.f;
        int j = s;
        for (; j + UNR <= e; j += UNR) {
            int c[UNR];
#pragma unroll
            for (int u = 0; u < UNR; ++u) c[u] = colx[j + u];
            float2 v[UNR];
#pragma unroll
            for (int u = 0; u < UNR; ++u) v[u] = gl[c[u] << 6];
#pragma unroll
            for (int u = 0; u < UNR; u += 2) {
                acc.x += v[u].x; acc.y += v[u].y;
                accx2 += v[u + 1].x; accy2 += v[u + 1].y;
            }
        }
        for (; j < e; ++j) {
            float2 v = gl[colx[j] << 6];
            acc.x += v.x; acc.y += v.y;
        }
        acc.x += accx2; acc.y += accy2;
        float d = dinv[wid];
        float2 bv = *(const float2*)&bias[lane * 2];
        float ox = fmaf(d, acc.x, bv.x);
        float oy = fmaf(d, acc.y, bv.y);
        if (RELU) { ox = fmaxf(ox, 0.f); oy = fmaxf(oy, 0.f); }
        float2 o; o.x = ox; o.y = oy;
        *(float2*)&Out[(size_t)wid * F + lane * 2] = o;
    } else {  // F == 64
        const float* gl = G + lane;                  // row stride 64 floats
        float acc = gl[wid << 6];                    // self
        float acc2 = 0.f;
        int j = s;
        for (; j + UNR <= e; j += UNR) {
            int c[UNR];
#pragma unroll
            for (int u = 0; u < UNR; ++u) c[u] = colx[j + u];
            float v[UNR];
#pragma unroll
            for (int u = 0; u < UNR; ++u) v[u] = gl[c[u] << 6];
#pragma unroll
            for (int u = 0; u < UNR; u += 2) { acc += v[u]; acc2 += v[u + 1]; }
        }
        for (; j < e; ++j) acc += gl[colx[j] << 6];
        acc += acc2;
        float o = fmaf(dinv[wid], acc, bias[lane]);
        if (RELU) o = fmaxf(o, 0.f);
        Out[(size_t)wid * F + lane] = o;
    }
}

extern "C" void kernel_launch(void* const* d_in, const int* in_sizes, int n_in,
                              void* d_out, int out_size, void* d_ws, size_t ws_size,
                              hipStream_t stream) {
    const float* x  = (const float*)d_in[0];
    const void*  ei = d_in[1];
    const float* w1 = (const float*)d_in[2];
    const float* b1 = (const float*)d_in[3];
    const float* w2 = (const float*)d_in[4];
    const float* b2 = (const float*)d_in[5];
    float* out = (float*)d_out;

    const int N  = in_sizes[0] / 128;   // 100000
    const int E  = in_sizes[1] / 2;     // 3200000
    const int NB = (N + 255) / 256;

    char* p = (char*)d_ws;
    auto carve = [&](size_t bytes) {
        void* r = (void*)p;
        p += (bytes + 255) & ~(size_t)255;
        return r;
    };
    int*   deg      = (int*)carve((size_t)N * 4);
    int*   rowptr   = (int*)carve((size_t)(N + 1) * 4);
    int*   cursor   = (int*)carve((size_t)N * 4);
    int*   partials = (int*)carve(512 * 4);
    int*   flag     = (int*)carve(256);
    float* dinv     = (float*)carve((size_t)N * 4);
    int*   colx     = (int*)carve((size_t)E * 4);
    float* g1       = (float*)carve((size_t)N * 128 * 4);
    float* a1       = (float*)carve((size_t)N * 128 * 4);
    float* g2       = g1;  // g1 dead after agg1; reuse

    hipMemsetAsync(deg, 0, (size_t)N * 4, stream);
    detect_i64<<<1, 64, 0, stream>>>((const int*)ei, flag);
    hist_kernel<<<(E + 255) / 256, 256, 0, stream>>>(ei, E, flag, deg);
    dinv_kernel<<<(N + 255) / 256, 256, 0, stream>>>(deg, dinv, N);
    scan_partials<<<NB, 256, 0, stream>>>(deg, partials, N);
    scan_scan<<<1, 512, 0, stream>>>(partials, NB);
    scan_write<<<NB, 256, 0, stream>>>(deg, partials, rowptr, cursor, N, E);
    fill_kernel<<<(E + 255) / 256, 256, 0, stream>>>(ei, E, flag, cursor, colx);

    dim3 grid1((N + 63) / 64, 2);
    gemm_scale<<<grid1, 256, 0, stream>>>(x, w1, dinv, g1, N, 128);
    agg_kernel<128, true, 8><<<(N + 3) / 4, 256, 0, stream>>>(g1, rowptr, colx, dinv, b1, a1, N);

    dim3 grid2((N + 63) / 64, 1);
    gemm_scale<<<grid2, 256, 0, stream>>>(a1, w2, dinv, g2, N, 64);
    agg_kernel<64, false, 16><<<(N + 3) / 4, 256, 0, stream>>>(g2, rowptr, colx, dinv, b2, out, N);
}

// Round 3
// 786.457 us; speedup vs baseline: 1.3934x; 1.0822x over previous
//
#include <hip/hip_runtime.h>

// 2-layer GCN: h1 = relu(Anorm @ (x@w1) + b1); out = Anorm @ (h1@w2) + b2
// CSR-by-dst built per call; dinv folded into GEMM epilogue; aggregation is a
// pure gather-sum, one wave per node, fully predicated batch-unrolled loop.
// R2->R3: fill/hist get 4 independent edge chains per thread (latency-bound);
// agg loses its serial tail (predicated pipeline).

// ---------------- edge dtype detect (int32 vs int64) ----------------
__global__ void detect_i64(const int* __restrict__ idx32, int* __restrict__ flag) {
    int v = idx32[2 * threadIdx.x + 1];
    unsigned long long b = __ballot(v != 0);
    if (threadIdx.x == 0) flag[0] = (b == 0ULL) ? 1 : 0;
}

__device__ __forceinline__ int load_idx(const void* edges, size_t i, int is64) {
    return is64 ? (int)((const long long*)edges)[i] : ((const int*)edges)[i];
}

// ---------------- degree histogram (4 edges/thread) ----------------
__global__ void hist_kernel(const void* __restrict__ edges, int E, int T,
                            const int* __restrict__ flag, int* __restrict__ deg) {
    int i = blockIdx.x * blockDim.x + threadIdx.x;
    int is64 = flag[0];
#pragma unroll
    for (int u = 0; u < 4; ++u) {
        int j = i + u * T;
        if (j < E) {
            int d = load_idx(edges, (size_t)E + j, is64);
            atomicAdd(&deg[d], 1);
        }
    }
}

__global__ void dinv_kernel(const int* __restrict__ deg, float* __restrict__ dinv, int N) {
    int i = blockIdx.x * blockDim.x + threadIdx.x;
    if (i < N) dinv[i] = rsqrtf((float)(deg[i] + 1));  // +1 for self-loop
}

// ---------------- 3-kernel exclusive scan over deg -> rowptr ----------------
__global__ void scan_partials(const int* __restrict__ deg, int* __restrict__ partials, int N) {
    __shared__ int sm[256];
    int t = threadIdx.x, i = blockIdx.x * 256 + t;
    sm[t] = (i < N) ? deg[i] : 0;
    __syncthreads();
    for (int off = 128; off > 0; off >>= 1) {
        if (t < off) sm[t] += sm[t + off];
        __syncthreads();
    }
    if (t == 0) partials[blockIdx.x] = sm[0];
}

__global__ void scan_scan(int* __restrict__ partials, int NB) {  // 1 block, 512 thr
    __shared__ int sm[512];
    int t = threadIdx.x;
    int v = (t < NB) ? partials[t] : 0;
    sm[t] = v; __syncthreads();
    for (int off = 1; off < 512; off <<= 1) {
        int x = sm[t];
        int y = (t >= off) ? sm[t - off] : 0;
        __syncthreads();
        sm[t] = x + y;
        __syncthreads();
    }
    if (t < NB) partials[t] = (t == 0) ? 0 : sm[t - 1];  // exclusive
}

__global__ void scan_write(const int* __restrict__ deg, const int* __restrict__ partials,
                           int* __restrict__ rowptr, int* __restrict__ cursor, int N, int E) {
    __shared__ int sm[256];
    int t = threadIdx.x, b = blockIdx.x, i = b * 256 + t;
    int v = (i < N) ? deg[i] : 0;
    sm[t] = v; __syncthreads();
    for (int off = 1; off < 256; off <<= 1) {
        int x = sm[t];
        int y = (t >= off) ? sm[t - off] : 0;
        __syncthreads();
        sm[t] = x + y;
        __syncthreads();
    }
    int ex = partials[b] + sm[t] - v;  // exclusive
    if (i < N) { rowptr[i] = ex; cursor[i] = ex; }
    if (i == 0 && b == 0) rowptr[N] = E;
}

// ------- counting-sort fill: 4 independent edge chains per thread -------
__global__ void fill_kernel(const void* __restrict__ edges, int E, int T,
                            const int* __restrict__ flag, int* __restrict__ cursor,
                            int* __restrict__ colx) {
    int i = blockIdx.x * blockDim.x + threadIdx.x;
    int is64 = flag[0];
    int s[4], d[4], pos[4];
    bool ok[4];
#pragma unroll
    for (int u = 0; u < 4; ++u) {
        int j = i + u * T;
        ok[u] = j < E;
        int jj = ok[u] ? j : 0;
        s[u] = load_idx(edges, (size_t)jj, is64);
        d[u] = load_idx(edges, (size_t)E + jj, is64);
    }
#pragma unroll
    for (int u = 0; u < 4; ++u)
        if (ok[u]) pos[u] = atomicAdd(&cursor[d[u]], 1);
#pragma unroll
    for (int u = 0; u < 4; ++u)
        if (ok[u]) colx[pos[u]] = s[u];
}

// ---------------- GEMM: G = dinv .* (X @ W), K=128 fixed ----------------
__global__ __launch_bounds__(256) void gemm_scale(
    const float* __restrict__ X, const float* __restrict__ W,
    const float* __restrict__ dinv, float* __restrict__ G, int M, int Ncols) {
    constexpr int K = 128;
    __shared__ float xT[K][64];   // [k][row]
    __shared__ float ws[K][64];   // [k][col]
    const int t = threadIdx.x;
    const int m0 = blockIdx.x * 64;
    const int c0 = blockIdx.y * 64;

    {
        int cl = (t & 15) * 4;
        int k0 = t >> 4;
        for (int kk = 0; kk < K; kk += 16) {
            int k = k0 + kk;
            float4 wv = *(const float4*)&W[(size_t)k * Ncols + c0 + cl];
            *(float4*)&ws[k][cl] = wv;
        }
    }
    {
        int r = t & 63, cg = t >> 6;
        int row = m0 + r;
        bool valid = row < M;
        const float* xrow = &X[(size_t)(valid ? row : (M - 1)) * K];
        for (int cc = 0; cc < 8; ++cc) {
            int c = cg * 4 + cc * 16;
            float4 v;
            if (valid) v = *(const float4*)&xrow[c];
            else { v.x = v.y = v.z = v.w = 0.f; }
            xT[c + 0][r] = v.x; xT[c + 1][r] = v.y;
            xT[c + 2][r] = v.z; xT[c + 3][r] = v.w;
        }
    }
    __syncthreads();

    const int tc = (t & 15) * 4;
    const int tr = (t >> 4) * 4;
    float acc[4][4] = {};
#pragma unroll 8
    for (int k = 0; k < K; ++k) {
        float4 av = *(const float4*)&xT[k][tr];
        float4 bv = *(const float4*)&ws[k][tc];
        float a[4] = {av.x, av.y, av.z, av.w};
        float b[4] = {bv.x, bv.y, bv.z, bv.w};
#pragma unroll
        for (int i = 0; i < 4; ++i)
#pragma unroll
            for (int j = 0; j < 4; ++j)
                acc[i][j] = fmaf(a[i], b[j], acc[i][j]);
    }

#pragma unroll
    for (int i = 0; i < 4; ++i) {
        int row = m0 + tr + i;
        if (row < M) {
            float d = dinv[row];
            float4 o;
            o.x = acc[i][0] * d; o.y = acc[i][1] * d;
            o.z = acc[i][2] * d; o.w = acc[i][3] * d;
            *(float4*)&G[(size_t)row * Ncols + c0 + tc] = o;
        }
    }
}

// ------- aggregation: out[i] = dinv[i]*(sum_nbr g[src] + g[i]) + b -------
// One wave per node; fully predicated UNR-deep gather pipeline (no serial tail).
template <int F, bool RELU, int UNR>
__global__ __launch_bounds__(256) void agg_kernel(
    const float* __restrict__ G, const int* __restrict__ rowptr,
    const int* __restrict__ colx, const float* __restrict__ dinv,
    const float* __restrict__ bias, float* __restrict__ Out, int N) {
    int wid = (int)((blockIdx.x * 256 + threadIdx.x) >> 6);
    int lane = threadIdx.x & 63;
    if (wid >= N) return;
    int s = rowptr[wid], e = rowptr[wid + 1];

    if constexpr (F == 128) {
        const float2* gl = (const float2*)G + lane;  // row stride 64 float2
        float2 acc = gl[(size_t)wid << 6];           // self-loop term
        float accx2 = 0.f, accy2 = 0.f;
        for (int j = s; j < e; j += UNR) {
            int c[UNR];
            float w[UNR];
#pragma unroll
            for (int u = 0; u < UNR; ++u) {
                int jj = j + u;
                bool m = jj < e;
                w[u] = m ? 1.f : 0.f;
                c[u] = colx[m ? jj : (e - 1)];
            }
            float2 v[UNR];
#pragma unroll
            for (int u = 0; u < UNR; ++u) v[u] = gl[(size_t)c[u] << 6];
#pragma unroll
            for (int u = 0; u < UNR; u += 2) {
                acc.x = fmaf(w[u], v[u].x, acc.x);
                acc.y = fmaf(w[u], v[u].y, acc.y);
                accx2 = fmaf(w[u + 1], v[u + 1].x, accx2);
                accy2 = fmaf(w[u + 1], v[u + 1].y, accy2);
            }
        }
        acc.x += accx2; acc.y += accy2;
        float d = dinv[wid];
        float2 bv = *(const float2*)&bias[lane * 2];
        float ox = fmaf(d, acc.x, bv.x);
        float oy = fmaf(d, acc.y, bv.y);
        if (RELU) { ox = fmaxf(ox, 0.f); oy = fmaxf(oy, 0.f); }
        float2 o; o.x = ox; o.y = oy;
        *(float2*)&Out[(size_t)wid * F + lane * 2] = o;
    } else {  // F == 64
        const float* gl = G + lane;                  // row stride 64 floats
        float acc = gl[(size_t)wid << 6];            // self
        float acc2 = 0.f;
        for (int j = s; j < e; j += UNR) {
            int c[UNR];
            float w[UNR];
#pragma unroll
            for (int u = 0; u < UNR; ++u) {
                int jj = j + u;
                bool m = jj < e;
                w[u] = m ? 1.f : 0.f;
                c[u] = colx[m ? jj : (e - 1)];
            }
            float v[UNR];
#pragma unroll
            for (int u = 0; u < UNR; ++u) v[u] = gl[(size_t)c[u] << 6];
#pragma unroll
            for (int u = 0; u < UNR; u += 2) {
                acc = fmaf(w[u], v[u], acc);
                acc2 = fmaf(w[u + 1], v[u + 1], acc2);
            }
        }
        acc += acc2;
        float o = fmaf(dinv[wid], acc, bias[lane]);
        if (RELU) o = fmaxf(o, 0.f);
        Out[(size_t)wid * F + lane] = o;
    }
}

extern "C" void kernel_launch(void* const* d_in, const int* in_sizes, int n_in,
                              void* d_out, int out_size, void* d_ws, size_t ws_size,
                              hipStream_t stream) {
    const float* x  = (const float*)d_in[0];
    const void*  ei = d_in[1];
    const float* w1 = (const float*)d_in[2];
    const float* b1 = (const float*)d_in[3];
    const float* w2 = (const float*)d_in[4];
    const float* b2 = (const float*)d_in[5];
    float* out = (float*)d_out;

    const int N  = in_sizes[0] / 128;   // 100000
    const int E  = in_sizes[1] / 2;     // 3200000
    const int NB = (N + 255) / 256;

    char* p = (char*)d_ws;
    auto carve = [&](size_t bytes) {
        void* r = (void*)p;
        p += (bytes + 255) & ~(size_t)255;
        return r;
    };
    int*   deg      = (int*)carve((size_t)N * 4);
    int*   rowptr   = (int*)carve((size_t)(N + 1) * 4);
    int*   cursor   = (int*)carve((size_t)N * 4);
    int*   partials = (int*)carve(512 * 4);
    int*   flag     = (int*)carve(256);
    float* dinv     = (float*)carve((size_t)N * 4);
    int*   colx     = (int*)carve((size_t)E * 4);
    float* g1       = (float*)carve((size_t)N * 128 * 4);
    float* a1       = (float*)carve((size_t)N * 128 * 4);
    float* g2       = g1;  // g1 dead after agg1; reuse

    // 4 edges per thread, grid-strided so each pass stays coalesced
    const int T4 = (E + 3) / 4;           // threads needed
    const int nb4 = (T4 + 255) / 256;

    hipMemsetAsync(deg, 0, (size_t)N * 4, stream);
    detect_i64<<<1, 64, 0, stream>>>((const int*)ei, flag);
    hist_kernel<<<nb4, 256, 0, stream>>>(ei, E, T4, flag, deg);
    dinv_kernel<<<(N + 255) / 256, 256, 0, stream>>>(deg, dinv, N);
    scan_partials<<<NB, 256, 0, stream>>>(deg, partials, N);
    scan_scan<<<1, 512, 0, stream>>>(partials, NB);
    scan_write<<<NB, 256, 0, stream>>>(deg, partials, rowptr, cursor, N, E);
    fill_kernel<<<nb4, 256, 0, stream>>>(ei, E, T4, flag, cursor, colx);

    dim3 grid1((N + 63) / 64, 2);
    gemm_scale<<<grid1, 256, 0, stream>>>(x, w1, dinv, g1, N, 128);
    agg_kernel<128, true, 8><<<(N + 3) / 4, 256, 0, stream>>>(g1, rowptr, colx, dinv, b1, a1, N);

    dim3 grid2((N + 63) / 64, 1);
    gemm_scale<<<grid2, 256, 0, stream>>>(a1, w2, dinv, g2, N, 64);
    agg_kernel<64, false, 16><<<(N + 3) / 4, 256, 0, stream>>>(g2, rowptr, colx, dinv, b2, out, N);
}

// Round 6
// 610.771 us; speedup vs baseline: 1.7942x; 1.2876x over previous
//
#include <hip/hip_runtime.h>

// 2-layer GCN: h1 = relu(Anorm @ (x@w1) + b1); out = Anorm @ (h1@w2) + b2
// CSR-by-dst built per call; rank fused into histogram (atomicAdd return);
// fill atomic-free. R5->R6: FIX -- hist/fill grids overlapped when T wasn't
// a multiple of 256 (128 extra threads re-processed 896 edges, leaving
// orphaned colx slots = 0xAA poison -> wild gather address -> abort).
// Guard `i >= T` makes the edge partition exact; agg clamps gathered
// indices as cheap insurance.

// ---------------- edge dtype detect (int32 vs int64) ----------------
__global__ void detect_i64(const int* __restrict__ idx32, int* __restrict__ flag) {
    int v = idx32[2 * threadIdx.x + 1];
    unsigned long long b = __ballot(v != 0);
    if (threadIdx.x == 0) flag[0] = (b == 0ULL) ? 1 : 0;
}

__device__ __forceinline__ int load_idx(const void* edges, size_t i, int is64) {
    return is64 ? (int)((const long long*)edges)[i] : ((const int*)edges)[i];
}

__device__ __forceinline__ int clampN(int v, int N) {
    return ((unsigned)v < (unsigned)N) ? v : 0;
}

// ------- degree histogram + rank capture (8 independent chains/thread) -------
__global__ void hist_kernel(const void* __restrict__ edges, int E, int T,
                            const int* __restrict__ flag, int* __restrict__ deg,
                            int* __restrict__ rank, int N) {
    int i = blockIdx.x * blockDim.x + threadIdx.x;
    if (i >= T) return;  // exact partition: thread i owns {i, i+T, ..., i+7T}
    int is64 = flag[0];
    int d[8];
    bool ok[8];
#pragma unroll
    for (int u = 0; u < 8; ++u) {
        int j = i + u * T;
        ok[u] = j < E;
        d[u] = clampN(load_idx(edges, (size_t)E + (ok[u] ? j : 0), is64), N);
    }
    int r[8];
#pragma unroll
    for (int u = 0; u < 8; ++u)
        if (ok[u]) r[u] = atomicAdd(&deg[d[u]], 1);
#pragma unroll
    for (int u = 0; u < 8; ++u)
        if (ok[u]) rank[i + u * T] = r[u];
}

__global__ void dinv_kernel(const int* __restrict__ deg, float* __restrict__ dinv, int N) {
    int i = blockIdx.x * blockDim.x + threadIdx.x;
    if (i < N) dinv[i] = rsqrtf((float)(deg[i] + 1));  // +1 for self-loop
}

// ---------------- 3-kernel exclusive scan over deg -> rowptr ----------------
__global__ void scan_partials(const int* __restrict__ deg, int* __restrict__ partials, int N) {
    __shared__ int sm[256];
    int t = threadIdx.x, i = blockIdx.x * 256 + t;
    sm[t] = (i < N) ? deg[i] : 0;
    __syncthreads();
    for (int off = 128; off > 0; off >>= 1) {
        if (t < off) sm[t] += sm[t + off];
        __syncthreads();
    }
    if (t == 0) partials[blockIdx.x] = sm[0];
}

__global__ void scan_scan(int* __restrict__ partials, int NB) {  // 1 block, 512 thr
    __shared__ int sm[512];
    int t = threadIdx.x;
    int v = (t < NB) ? partials[t] : 0;
    sm[t] = v; __syncthreads();
    for (int off = 1; off < 512; off <<= 1) {
        int x = sm[t];
        int y = (t >= off) ? sm[t - off] : 0;
        __syncthreads();
        sm[t] = x + y;
        __syncthreads();
    }
    if (t < NB) partials[t] = (t == 0) ? 0 : sm[t - 1];  // exclusive
}

__global__ void scan_write(const int* __restrict__ deg, const int* __restrict__ partials,
                           int* __restrict__ rowptr, int N, int E) {
    __shared__ int sm[256];
    int t = threadIdx.x, b = blockIdx.x, i = b * 256 + t;
    int v = (i < N) ? deg[i] : 0;
    sm[t] = v; __syncthreads();
    for (int off = 1; off < 256; off <<= 1) {
        int x = sm[t];
        int y = (t >= off) ? sm[t - off] : 0;
        __syncthreads();
        sm[t] = x + y;
        __syncthreads();
    }
    int ex = partials[b] + sm[t] - v;  // exclusive
    if (i < N) rowptr[i] = ex;
    if (i == 0 && b == 0) rowptr[N] = E;
}

// ------- atomic-free fill: colx[rowptr[d] + rank] = s -------
__global__ void fill_kernel(const void* __restrict__ edges, int E, int T,
                            const int* __restrict__ flag,
                            const int* __restrict__ rowptr,
                            const int* __restrict__ rank,
                            int* __restrict__ colx, int N) {
    int i = blockIdx.x * blockDim.x + threadIdx.x;
    if (i >= T) return;  // exact partition
    int is64 = flag[0];
    int s[4], d[4], r[4];
    bool ok[4];
#pragma unroll
    for (int u = 0; u < 4; ++u) {
        int j = i + u * T;
        ok[u] = j < E;
        int jj = ok[u] ? j : 0;
        s[u] = clampN(load_idx(edges, (size_t)jj, is64), N);
        d[u] = clampN(load_idx(edges, (size_t)E + jj, is64), N);
        r[u] = rank[jj];
    }
#pragma unroll
    for (int u = 0; u < 4; ++u)
        if (ok[u]) colx[rowptr[d[u]] + r[u]] = s[u];
}

// ---------------- GEMM: G = dinv .* (X @ W), K=128 fixed ----------------
__global__ __launch_bounds__(256) void gemm_scale(
    const float* __restrict__ X, const float* __restrict__ W,
    const float* __restrict__ dinv, float* __restrict__ G, int M, int Ncols) {
    constexpr int K = 128;
    __shared__ float xT[K][64];   // [k][row]
    __shared__ float ws[K][64];   // [k][col]
    const int t = threadIdx.x;
    const int m0 = blockIdx.x * 64;
    const int c0 = blockIdx.y * 64;

    {
        int cl = (t & 15) * 4;
        int k0 = t >> 4;
        for (int kk = 0; kk < K; kk += 16) {
            int k = k0 + kk;
            float4 wv = *(const float4*)&W[(size_t)k * Ncols + c0 + cl];
            *(float4*)&ws[k][cl] = wv;
        }
    }
    {
        int r = t & 63, cg = t >> 6;
        int row = m0 + r;
        bool valid = row < M;
        const float* xrow = &X[(size_t)(valid ? row : (M - 1)) * K];
        for (int cc = 0; cc < 8; ++cc) {
            int c = cg * 4 + cc * 16;
            float4 v;
            if (valid) v = *(const float4*)&xrow[c];
            else { v.x = v.y = v.z = v.w = 0.f; }
            xT[c + 0][r] = v.x; xT[c + 1][r] = v.y;
            xT[c + 2][r] = v.z; xT[c + 3][r] = v.w;
        }
    }
    __syncthreads();

    const int tc = (t & 15) * 4;
    const int tr = (t >> 4) * 4;
    float acc[4][4] = {};
#pragma unroll 8
    for (int k = 0; k < K; ++k) {
        float4 av = *(const float4*)&xT[k][tr];
        float4 bv = *(const float4*)&ws[k][tc];
        float a[4] = {av.x, av.y, av.z, av.w};
        float b[4] = {bv.x, bv.y, bv.z, bv.w};
#pragma unroll
        for (int i = 0; i < 4; ++i)
#pragma unroll
            for (int j = 0; j < 4; ++j)
                acc[i][j] = fmaf(a[i], b[j], acc[i][j]);
    }

#pragma unroll
    for (int i = 0; i < 4; ++i) {
        int row = m0 + tr + i;
        if (row < M) {
            float d = dinv[row];
            float4 o;
            o.x = acc[i][0] * d; o.y = acc[i][1] * d;
            o.z = acc[i][2] * d; o.w = acc[i][3] * d;
            *(float4*)&G[(size_t)row * Ncols + c0 + tc] = o;
        }
    }
}

// ------- aggregation: out[i] = dinv[i]*(sum_nbr g[src] + g[i]) + b -------
// One wave per node; fully predicated UNR-deep gather pipeline; gathered
// indices clamped to [0,N) (crash insurance, ~2 VALU vs 500-cy gathers).
template <int F, bool RELU, int UNR>
__global__ __launch_bounds__(256) void agg_kernel(
    const float* __restrict__ G, const int* __restrict__ rowptr,
    const int* __restrict__ colx, const float* __restrict__ dinv,
    const float* __restrict__ bias, float* __restrict__ Out, int N) {
    int wid = (int)((blockIdx.x * 256 + threadIdx.x) >> 6);
    int lane = threadIdx.x & 63;
    if (wid >= N) return;
    int s = rowptr[wid], e = rowptr[wid + 1];

    if constexpr (F == 128) {
        const float2* gl = (const float2*)G + lane;  // row stride 64 float2
        float2 acc = gl[(size_t)wid << 6];           // self-loop term
        float accx2 = 0.f, accy2 = 0.f;
        for (int j = s; j < e; j += UNR) {
            int c[UNR];
            float w[UNR];
#pragma unroll
            for (int u = 0; u < UNR; ++u) {
                int jj = j + u;
                bool m = jj < e;
                w[u] = m ? 1.f : 0.f;
                c[u] = clampN(colx[m ? jj : (e - 1)], N);
            }
            float2 v[UNR];
#pragma unroll
            for (int u = 0; u < UNR; ++u) v[u] = gl[(size_t)c[u] << 6];
#pragma unroll
            for (int u = 0; u < UNR; u += 2) {
                acc.x = fmaf(w[u], v[u].x, acc.x);
                acc.y = fmaf(w[u], v[u].y, acc.y);
                accx2 = fmaf(w[u + 1], v[u + 1].x, accx2);
                accy2 = fmaf(w[u + 1], v[u + 1].y, accy2);
            }
        }
        acc.x += accx2; acc.y += accy2;
        float d = dinv[wid];
        float2 bv = *(const float2*)&bias[lane * 2];
        float ox = fmaf(d, acc.x, bv.x);
        float oy = fmaf(d, acc.y, bv.y);
        if (RELU) { ox = fmaxf(ox, 0.f); oy = fmaxf(oy, 0.f); }
        float2 o; o.x = ox; o.y = oy;
        *(float2*)&Out[(size_t)wid * F + lane * 2] = o;
    } else {  // F == 64
        const float* gl = G + lane;                  // row stride 64 floats
        float acc = gl[(size_t)wid << 6];            // self
        float acc2 = 0.f;
        for (int j = s; j < e; j += UNR) {
            int c[UNR];
            float w[UNR];
#pragma unroll
            for (int u = 0; u < UNR; ++u) {
                int jj = j + u;
                bool m = jj < e;
                w[u] = m ? 1.f : 0.f;
                c[u] = clampN(colx[m ? jj : (e - 1)], N);
            }
            float v[UNR];
#pragma unroll
            for (int u = 0; u < UNR; ++u) v[u] = gl[(size_t)c[u] << 6];
#pragma unroll
            for (int u = 0; u < UNR; u += 2) {
                acc = fmaf(w[u], v[u], acc);
                acc2 = fmaf(w[u + 1], v[u + 1], acc2);
            }
        }
        acc += acc2;
        float o = fmaf(dinv[wid], acc, bias[lane]);
        if (RELU) o = fmaxf(o, 0.f);
        Out[(size_t)wid * F + lane] = o;
    }
}

extern "C" void kernel_launch(void* const* d_in, const int* in_sizes, int n_in,
                              void* d_out, int out_size, void* d_ws, size_t ws_size,
                              hipStream_t stream) {
    const float* x  = (const float*)d_in[0];
    const void*  ei = d_in[1];
    const float* w1 = (const float*)d_in[2];
    const float* b1 = (const float*)d_in[3];
    const float* w2 = (const float*)d_in[4];
    const float* b2 = (const float*)d_in[5];
    float* out = (float*)d_out;

    const int N  = in_sizes[0] / 128;   // 100000
    const int E  = in_sizes[1] / 2;     // 3200000
    const int NB = (N + 255) / 256;

    char* p = (char*)d_ws;
    auto carve = [&](size_t bytes) {
        void* r = (void*)p;
        p += (bytes + 255) & ~(size_t)255;
        return r;
    };
    int*   deg      = (int*)carve((size_t)N * 4);
    int*   rowptr   = (int*)carve((size_t)(N + 1) * 4);
    int*   partials = (int*)carve(512 * 4);
    int*   flag     = (int*)carve(256);
    float* dinv     = (float*)carve((size_t)N * 4);
    int*   colx     = (int*)carve((size_t)E * 4);
    float* g1       = (float*)carve((size_t)N * 128 * 4);
    float* a1       = (float*)carve((size_t)N * 128 * 4);
    float* g2       = g1;         // g1 dead after agg1; reuse
    int*   rank     = (int*)a1;   // rank dead before agg1 writes a1

    const int T8 = (E + 7) / 8;           // hist: 8 edges/thread
    const int nb8 = (T8 + 255) / 256;
    const int T4 = (E + 3) / 4;           // fill: 4 edges/thread
    const int nb4 = (T4 + 255) / 256;

    hipMemsetAsync(deg, 0, (size_t)N * 4, stream);
    detect_i64<<<1, 64, 0, stream>>>((const int*)ei, flag);
    hist_kernel<<<nb8, 256, 0, stream>>>(ei, E, T8, flag, deg, rank, N);
    dinv_kernel<<<(N + 255) / 256, 256, 0, stream>>>(deg, dinv, N);
    scan_partials<<<NB, 256, 0, stream>>>(deg, partials, N);
    scan_scan<<<1, 512, 0, stream>>>(partials, NB);
    scan_write<<<NB, 256, 0, stream>>>(deg, partials, rowptr, N, E);
    fill_kernel<<<nb4, 256, 0, stream>>>(ei, E, T4, flag, rowptr, rank, colx, N);

    dim3 grid1((N + 63) / 64, 2);
    gemm_scale<<<grid1, 256, 0, stream>>>(x, w1, dinv, g1, N, 128);
    agg_kernel<128, true, 8><<<(N + 3) / 4, 256, 0, stream>>>(g1, rowptr, colx, dinv, b1, a1, N);

    dim3 grid2((N + 63) / 64, 1);
    gemm_scale<<<grid2, 256, 0, stream>>>(a1, w2, dinv, g2, N, 64);
    agg_kernel<64, false, 16><<<(N + 3) / 4, 256, 0, stream>>>(g2, rowptr, colx, dinv, b2, out, N);
}

// Round 7
// 489.219 us; speedup vs baseline: 2.2399x; 1.2485x over previous
//
#include <hip/hip_runtime.h>

// 2-layer GCN: h1 = relu(Anorm @ (x@w1) + b1); out = Anorm @ (h1@w2) + b2
// CSR-by-dst built per call; rank fused into histogram; fill atomic-free.
// R6->R7: gather tables G stored as bf16 (f32 accumulate) -- halves the
// dominant gather traffic (agg1 774MB L2-miss @ 3.6 TB/s was the top cost);
// agg UNR deepened to 16 (VGPR headroom: 28 used).

// ---------------- edge dtype detect (int32 vs int64) ----------------
__global__ void detect_i64(const int* __restrict__ idx32, int* __restrict__ flag) {
    int v = idx32[2 * threadIdx.x + 1];
    unsigned long long b = __ballot(v != 0);
    if (threadIdx.x == 0) flag[0] = (b == 0ULL) ? 1 : 0;
}

__device__ __forceinline__ int load_idx(const void* edges, size_t i, int is64) {
    return is64 ? (int)((const long long*)edges)[i] : ((const int*)edges)[i];
}

__device__ __forceinline__ int clampN(int v, int N) {
    return ((unsigned)v < (unsigned)N) ? v : 0;
}

__device__ __forceinline__ ushort f2bf(float f) {  // RNE f32->bf16
    unsigned x = __float_as_uint(f);
    return (ushort)((x + 0x7FFF + ((x >> 16) & 1)) >> 16);
}
__device__ __forceinline__ float bf_lo(unsigned u) { return __uint_as_float(u << 16); }
__device__ __forceinline__ float bf_hi(unsigned u) { return __uint_as_float(u & 0xFFFF0000u); }
__device__ __forceinline__ float bf1(ushort u) { return __uint_as_float((unsigned)u << 16); }

// ------- degree histogram + rank capture (8 independent chains/thread) -------
__global__ void hist_kernel(const void* __restrict__ edges, int E, int T,
                            const int* __restrict__ flag, int* __restrict__ deg,
                            int* __restrict__ rank, int N) {
    int i = blockIdx.x * blockDim.x + threadIdx.x;
    if (i >= T) return;  // exact partition: thread i owns {i, i+T, ..., i+7T}
    int is64 = flag[0];
    int d[8];
    bool ok[8];
#pragma unroll
    for (int u = 0; u < 8; ++u) {
        int j = i + u * T;
        ok[u] = j < E;
        d[u] = clampN(load_idx(edges, (size_t)E + (ok[u] ? j : 0), is64), N);
    }
    int r[8];
#pragma unroll
    for (int u = 0; u < 8; ++u)
        if (ok[u]) r[u] = atomicAdd(&deg[d[u]], 1);
#pragma unroll
    for (int u = 0; u < 8; ++u)
        if (ok[u]) rank[i + u * T] = r[u];
}

__global__ void dinv_kernel(const int* __restrict__ deg, float* __restrict__ dinv, int N) {
    int i = blockIdx.x * blockDim.x + threadIdx.x;
    if (i < N) dinv[i] = rsqrtf((float)(deg[i] + 1));  // +1 for self-loop
}

// ---------------- 3-kernel exclusive scan over deg -> rowptr ----------------
__global__ void scan_partials(const int* __restrict__ deg, int* __restrict__ partials, int N) {
    __shared__ int sm[256];
    int t = threadIdx.x, i = blockIdx.x * 256 + t;
    sm[t] = (i < N) ? deg[i] : 0;
    __syncthreads();
    for (int off = 128; off > 0; off >>= 1) {
        if (t < off) sm[t] += sm[t + off];
        __syncthreads();
    }
    if (t == 0) partials[blockIdx.x] = sm[0];
}

__global__ void scan_scan(int* __restrict__ partials, int NB) {  // 1 block, 512 thr
    __shared__ int sm[512];
    int t = threadIdx.x;
    int v = (t < NB) ? partials[t] : 0;
    sm[t] = v; __syncthreads();
    for (int off = 1; off < 512; off <<= 1) {
        int x = sm[t];
        int y = (t >= off) ? sm[t - off] : 0;
        __syncthreads();
        sm[t] = x + y;
        __syncthreads();
    }
    if (t < NB) partials[t] = (t == 0) ? 0 : sm[t - 1];  // exclusive
}

__global__ void scan_write(const int* __restrict__ deg, const int* __restrict__ partials,
                           int* __restrict__ rowptr, int N, int E) {
    __shared__ int sm[256];
    int t = threadIdx.x, b = blockIdx.x, i = b * 256 + t;
    int v = (i < N) ? deg[i] : 0;
    sm[t] = v; __syncthreads();
    for (int off = 1; off < 256; off <<= 1) {
        int x = sm[t];
        int y = (t >= off) ? sm[t - off] : 0;
        __syncthreads();
        sm[t] = x + y;
        __syncthreads();
    }
    int ex = partials[b] + sm[t] - v;  // exclusive
    if (i < N) rowptr[i] = ex;
    if (i == 0 && b == 0) rowptr[N] = E;
}

// ------- atomic-free fill: colx[rowptr[d] + rank] = s -------
__global__ void fill_kernel(const void* __restrict__ edges, int E, int T,
                            const int* __restrict__ flag,
                            const int* __restrict__ rowptr,
                            const int* __restrict__ rank,
                            int* __restrict__ colx, int N) {
    int i = blockIdx.x * blockDim.x + threadIdx.x;
    if (i >= T) return;  // exact partition
    int is64 = flag[0];
    int s[4], d[4], r[4];
    bool ok[4];
#pragma unroll
    for (int u = 0; u < 4; ++u) {
        int j = i + u * T;
        ok[u] = j < E;
        int jj = ok[u] ? j : 0;
        s[u] = clampN(load_idx(edges, (size_t)jj, is64), N);
        d[u] = clampN(load_idx(edges, (size_t)E + jj, is64), N);
        r[u] = rank[jj];
    }
#pragma unroll
    for (int u = 0; u < 4; ++u)
        if (ok[u]) colx[rowptr[d[u]] + r[u]] = s[u];
}

// ------- GEMM: G = bf16( dinv .* (X @ W) ), K=128 fixed -------
__global__ __launch_bounds__(256) void gemm_scale(
    const float* __restrict__ X, const float* __restrict__ W,
    const float* __restrict__ dinv, ushort* __restrict__ G, int M, int Ncols) {
    constexpr int K = 128;
    __shared__ float xT[K][64];   // [k][row]
    __shared__ float ws[K][64];   // [k][col]
    const int t = threadIdx.x;
    const int m0 = blockIdx.x * 64;
    const int c0 = blockIdx.y * 64;

    {
        int cl = (t & 15) * 4;
        int k0 = t >> 4;
        for (int kk = 0; kk < K; kk += 16) {
            int k = k0 + kk;
            float4 wv = *(const float4*)&W[(size_t)k * Ncols + c0 + cl];
            *(float4*)&ws[k][cl] = wv;
        }
    }
    {
        int r = t & 63, cg = t >> 6;
        int row = m0 + r;
        bool valid = row < M;
        const float* xrow = &X[(size_t)(valid ? row : (M - 1)) * K];
        for (int cc = 0; cc < 8; ++cc) {
            int c = cg * 4 + cc * 16;
            float4 v;
            if (valid) v = *(const float4*)&xrow[c];
            else { v.x = v.y = v.z = v.w = 0.f; }
            xT[c + 0][r] = v.x; xT[c + 1][r] = v.y;
            xT[c + 2][r] = v.z; xT[c + 3][r] = v.w;
        }
    }
    __syncthreads();

    const int tc = (t & 15) * 4;
    const int tr = (t >> 4) * 4;
    float acc[4][4] = {};
#pragma unroll 8
    for (int k = 0; k < K; ++k) {
        float4 av = *(const float4*)&xT[k][tr];
        float4 bv = *(const float4*)&ws[k][tc];
        float a[4] = {av.x, av.y, av.z, av.w};
        float b[4] = {bv.x, bv.y, bv.z, bv.w};
#pragma unroll
        for (int i = 0; i < 4; ++i)
#pragma unroll
            for (int j = 0; j < 4; ++j)
                acc[i][j] = fmaf(a[i], b[j], acc[i][j]);
    }

#pragma unroll
    for (int i = 0; i < 4; ++i) {
        int row = m0 + tr + i;
        if (row < M) {
            float d = dinv[row];
            ushort4 o;
            o.x = f2bf(acc[i][0] * d); o.y = f2bf(acc[i][1] * d);
            o.z = f2bf(acc[i][2] * d); o.w = f2bf(acc[i][3] * d);
            *(ushort4*)&G[(size_t)row * Ncols + c0 + tc] = o;
        }
    }
}

// ------- aggregation: out[i] = dinv[i]*(sum_nbr g[src] + g[i]) + b -------
// One wave per node; bf16 gather table, f32 accumulate; fully predicated
// UNR-deep gather pipeline; gathered indices clamped to [0,N).
template <int F, bool RELU, int UNR>
__global__ __launch_bounds__(256) void agg_kernel(
    const ushort* __restrict__ G, const int* __restrict__ rowptr,
    const int* __restrict__ colx, const float* __restrict__ dinv,
    const float* __restrict__ bias, float* __restrict__ Out, int N) {
    int wid = (int)((blockIdx.x * 256 + threadIdx.x) >> 6);
    int lane = threadIdx.x & 63;
    if (wid >= N) return;
    int s = rowptr[wid], e = rowptr[wid + 1];

    if constexpr (F == 128) {
        const unsigned* gp = (const unsigned*)G;     // row = 64 dwords (2 bf16 each)
        unsigned su = gp[((size_t)wid << 6) + lane]; // self-loop term
        float ax = bf_lo(su), ay = bf_hi(su);
        float ax2 = 0.f, ay2 = 0.f;
        for (int j = s; j < e; j += UNR) {
            int c[UNR];
            float w[UNR];
#pragma unroll
            for (int u = 0; u < UNR; ++u) {
                int jj = j + u;
                bool m = jj < e;
                w[u] = m ? 1.f : 0.f;
                c[u] = clampN(colx[m ? jj : (e - 1)], N);
            }
            unsigned v[UNR];
#pragma unroll
            for (int u = 0; u < UNR; ++u) v[u] = gp[((size_t)c[u] << 6) + lane];
#pragma unroll
            for (int u = 0; u < UNR; u += 2) {
                ax  = fmaf(w[u],     bf_lo(v[u]),     ax);
                ay  = fmaf(w[u],     bf_hi(v[u]),     ay);
                ax2 = fmaf(w[u + 1], bf_lo(v[u + 1]), ax2);
                ay2 = fmaf(w[u + 1], bf_hi(v[u + 1]), ay2);
            }
        }
        ax += ax2; ay += ay2;
        float d = dinv[wid];
        float2 bv = *(const float2*)&bias[lane * 2];
        float ox = fmaf(d, ax, bv.x);
        float oy = fmaf(d, ay, bv.y);
        if (RELU) { ox = fmaxf(ox, 0.f); oy = fmaxf(oy, 0.f); }
        float2 o; o.x = ox; o.y = oy;
        *(float2*)&Out[(size_t)wid * F + lane * 2] = o;
    } else {  // F == 64
        const ushort* gp = G;                        // row = 64 bf16
        float acc = bf1(gp[((size_t)wid << 6) + lane]);  // self
        float acc2 = 0.f;
        for (int j = s; j < e; j += UNR) {
            int c[UNR];
            float w[UNR];
#pragma unroll
            for (int u = 0; u < UNR; ++u) {
                int jj = j + u;
                bool m = jj < e;
                w[u] = m ? 1.f : 0.f;
                c[u] = clampN(colx[m ? jj : (e - 1)], N);
            }
            ushort v[UNR];
#pragma unroll
            for (int u = 0; u < UNR; ++u) v[u] = gp[((size_t)c[u] << 6) + lane];
#pragma unroll
            for (int u = 0; u < UNR; u += 2) {
                acc  = fmaf(w[u],     bf1(v[u]),     acc);
                acc2 = fmaf(w[u + 1], bf1(v[u + 1]), acc2);
            }
        }
        acc += acc2;
        float o = fmaf(dinv[wid], acc, bias[lane]);
        if (RELU) o = fmaxf(o, 0.f);
        Out[(size_t)wid * F + lane] = o;
    }
}

extern "C" void kernel_launch(void* const* d_in, const int* in_sizes, int n_in,
                              void* d_out, int out_size, void* d_ws, size_t ws_size,
                              hipStream_t stream) {
    const float* x  = (const float*)d_in[0];
    const void*  ei = d_in[1];
    const float* w1 = (const float*)d_in[2];
    const float* b1 = (const float*)d_in[3];
    const float* w2 = (const float*)d_in[4];
    const float* b2 = (const float*)d_in[5];
    float* out = (float*)d_out;

    const int N  = in_sizes[0] / 128;   // 100000
    const int E  = in_sizes[1] / 2;     // 3200000
    const int NB = (N + 255) / 256;

    char* p = (char*)d_ws;
    auto carve = [&](size_t bytes) {
        void* r = (void*)p;
        p += (bytes + 255) & ~(size_t)255;
        return r;
    };
    int*    deg      = (int*)carve((size_t)N * 4);
    int*    rowptr   = (int*)carve((size_t)(N + 1) * 4);
    int*    partials = (int*)carve(512 * 4);
    int*    flag     = (int*)carve(256);
    float*  dinv     = (float*)carve((size_t)N * 4);
    int*    colx     = (int*)carve((size_t)E * 4);
    ushort* g1       = (ushort*)carve((size_t)N * 128 * 2);  // bf16 gather table
    float*  a1       = (float*)carve((size_t)N * 128 * 4);
    ushort* g2       = g1;        // g1 dead after agg1; reuse (N*64*2 fits)
    int*    rank     = (int*)a1;  // rank dead before agg1 writes a1

    const int T8 = (E + 7) / 8;           // hist: 8 edges/thread
    const int nb8 = (T8 + 255) / 256;
    const int T4 = (E + 3) / 4;           // fill: 4 edges/thread
    const int nb4 = (T4 + 255) / 256;

    hipMemsetAsync(deg, 0, (size_t)N * 4, stream);
    detect_i64<<<1, 64, 0, stream>>>((const int*)ei, flag);
    hist_kernel<<<nb8, 256, 0, stream>>>(ei, E, T8, flag, deg, rank, N);
    dinv_kernel<<<(N + 255) / 256, 256, 0, stream>>>(deg, dinv, N);
    scan_partials<<<NB, 256, 0, stream>>>(deg, partials, N);
    scan_scan<<<1, 512, 0, stream>>>(partials, NB);
    scan_write<<<NB, 256, 0, stream>>>(deg, partials, rowptr, N, E);
    fill_kernel<<<nb4, 256, 0, stream>>>(ei, E, T4, flag, rowptr, rank, colx, N);

    dim3 grid1((N + 63) / 64, 2);
    gemm_scale<<<grid1, 256, 0, stream>>>(x, w1, dinv, g1, N, 128);
    agg_kernel<128, true, 16><<<(N + 3) / 4, 256, 0, stream>>>(g1, rowptr, colx, dinv, b1, a1, N);

    dim3 grid2((N + 63) / 64, 1);
    gemm_scale<<<grid2, 256, 0, stream>>>(a1, w2, dinv, g2, N, 64);
    agg_kernel<64, false, 16><<<(N + 3) / 4, 256, 0, stream>>>(g2, rowptr, colx, dinv, b2, out, N);
}